// Round 1
// baseline (87.043 us; speedup 1.0000x reference)
//
#include <hip/hip_runtime.h>
#include <math.h>

#define NXg 302
#define NYg 394
#define Bb  16
#define Dd  128
#define Kk  16
#define UNITS 96
#define Gg  (NXg * NYg)          // 118988, divisible by 4
#define G4  (Gg / 4)             // 29747

static constexpr float SCALE_S   = 0.84932184f;   // sqrt(0.5 * log2(e))
static constexpr float INV_SCALE = 1.0f / 0.84932184f;
static constexpr float INV_TWO_PI = 0.15915494309f;

__device__ __forceinline__ float fast_exp2(float x) {
#if __has_builtin(__builtin_amdgcn_exp2f)
    return __builtin_amdgcn_exp2f(x);
#else
    return exp2f(x);
#endif
}

// ---------------------------------------------------------------------------
// Kernel 1: y = in @ w + b; derive per-(b,k) params:
//   [mu0, mu1, a/s, s/L11, s/L22, weight/(2*pi*L11*L22), 0, 0]  (8 floats)
// ---------------------------------------------------------------------------
__global__ __launch_bounds__(256) void mdn_setup(
    const float* __restrict__ in,     // [B][D]
    const float* __restrict__ w,      // [D][UNITS]
    const float* __restrict__ bias,   // [UNITS]
    float* __restrict__ params)       // [B][K][8]
{
    __shared__ float ysh[Bb][UNITS];
    const int t = threadIdx.x;

    for (int idx = t; idx < Bb * UNITS; idx += 256) {
        const int bb = idx / UNITS;
        const int u  = idx - bb * UNITS;
        const float* ir = in + bb * Dd;
        float a0 = 0.f, a1 = 0.f, a2 = 0.f, a3 = 0.f;
        #pragma unroll 8
        for (int d = 0; d < Dd; d += 4) {
            a0 = fmaf(ir[d + 0], w[(d + 0) * UNITS + u], a0);
            a1 = fmaf(ir[d + 1], w[(d + 1) * UNITS + u], a1);
            a2 = fmaf(ir[d + 2], w[(d + 2) * UNITS + u], a2);
            a3 = fmaf(ir[d + 3], w[(d + 3) * UNITS + u], a3);
        }
        ysh[bb][u] = (a0 + a1) + (a2 + a3) + bias[u];
    }
    __syncthreads();

    if (t < Bb) {
        // softmax over pi = y[t][80..95]
        float pi[Kk];
        float pmax = -3.4e38f;
        #pragma unroll
        for (int k = 0; k < Kk; ++k) {
            pi[k] = ysh[t][5 * Kk + k];
            pmax = fmaxf(pmax, pi[k]);
        }
        float sum = 0.f;
        #pragma unroll
        for (int k = 0; k < Kk; ++k) {
            pi[k] = __expf(pi[k] - pmax);
            sum += pi[k];
        }
        const float invsum = 1.0f / sum;

        #pragma unroll
        for (int k = 0; k < Kk; ++k) {
            const float mu0 = ysh[t][2 * k];
            const float mu1 = ysh[t][2 * k + 1];
            const float a   = ysh[t][2 * Kk + 3 * k + 0];
            const float l22 = __expf(ysh[t][2 * Kk + 3 * k + 1]);
            const float l11 = __expf(ysh[t][2 * Kk + 3 * k + 2]);
            const float wgt = pi[k] * invsum;
            const float c   = wgt * INV_TWO_PI / (l11 * l22);
            float* o = params + (t * Kk + k) * 8;
            o[0] = mu0;
            o[1] = mu1;
            o[2] = a * INV_SCALE;
            o[3] = SCALE_S / l11;
            o[4] = SCALE_S / l22;
            o[5] = c;
            o[6] = 0.f;
            o[7] = 0.f;
        }
    }
}

// ---------------------------------------------------------------------------
// Kernel 2: out[b][g] = sum_k c_k * exp2(-(z1'^2 + z2'^2))
// Each thread computes 4 consecutive g points; float4 store.
// ---------------------------------------------------------------------------
__global__ __launch_bounds__(256) void mdn_eval(
    const float4* __restrict__ params,   // [B][K][2] float4
    float* __restrict__ out)             // [B][G]
{
    const int b = blockIdx.y;
    const unsigned gid = blockIdx.x * 256u + threadIdx.x;
    if (gid >= (unsigned)G4) return;

    const unsigned g0 = gid * 4u;
    const unsigned i0 = g0 / (unsigned)NYg;     // magic-mul division
    const unsigned j0 = g0 - i0 * (unsigned)NYg;

    float px[4], py[4];
    #pragma unroll
    for (int t = 0; t < 4; ++t) {
        unsigned j = j0 + (unsigned)t;
        unsigned ii = i0;
        if (j >= (unsigned)NYg) { j -= (unsigned)NYg; ii += 1u; }
        px[t] = (float)ii * (1.0f / (float)(NXg - 1));
        py[t] = (float)j  * (1.0f / (float)(NYg - 1));
    }

    float acc[4] = {0.f, 0.f, 0.f, 0.f};
    const float4* pb = params + b * Kk * 2;

    #pragma unroll
    for (int k = 0; k < Kk; ++k) {
        const float4 lo = pb[2 * k];       // uniform -> scalar loads
        const float4 hi = pb[2 * k + 1];
        const float mu0 = lo.x, mu1 = lo.y, ap = lo.z, i11 = lo.w;
        const float i22 = hi.x, c = hi.y;
        #pragma unroll
        for (int t = 0; t < 4; ++t) {
            const float z1 = (px[t] - mu0) * i11;
            const float z2 = fmaf(-ap, z1, (py[t] - mu1)) * i22;
            const float m  = fmaf(z2, z2, z1 * z1);
            acc[t] = fmaf(c, fast_exp2(-m), acc[t]);
        }
    }

    float4 r;
    r.x = acc[0]; r.y = acc[1]; r.z = acc[2]; r.w = acc[3];
    reinterpret_cast<float4*>(out + (size_t)b * Gg)[gid] = r;
}

// ---------------------------------------------------------------------------
extern "C" void kernel_launch(void* const* d_in, const int* in_sizes, int n_in,
                              void* d_out, int out_size, void* d_ws, size_t ws_size,
                              hipStream_t stream) {
    const float* in   = (const float*)d_in[0];   // [16][128]
    const float* w    = (const float*)d_in[1];   // [128][96]
    const float* bias = (const float*)d_in[2];   // [96]
    float* out        = (float*)d_out;           // [16][302][394]
    float* params     = (float*)d_ws;            // [16][16][8] = 8 KiB

    mdn_setup<<<dim3(1, 1, 1), dim3(256, 1, 1), 0, stream>>>(in, w, bias, params);

    dim3 grid((G4 + 255) / 256, Bb, 1);          // (117, 16)
    mdn_eval<<<grid, dim3(256, 1, 1), 0, stream>>>(
        reinterpret_cast<const float4*>(params), out);
}

// Round 2
// 68.974 us; speedup vs baseline: 1.2620x; 1.2620x over previous
//
#include <hip/hip_runtime.h>
#include <math.h>

#define NXg 302
#define NYg 394
#define Bb  16
#define Dd  128
#define Kk  16
#define UNITS 96
#define Gg  (NXg * NYg)          // 118988
#define JT  99                   // ceil(394/4) 4-point j-groups per row
#define THREADS_PER_B (NXg * JT) // 29898

static constexpr float SCALE_S    = 0.84932184f;   // sqrt(0.5 * log2(e))
static constexpr float INV_SCALE  = 1.0f / 0.84932184f;
static constexpr float INV_TWO_PI = 0.15915494309f;

__device__ __forceinline__ float fast_exp2(float x) {
#if __has_builtin(__builtin_amdgcn_exp2f)
    return __builtin_amdgcn_exp2f(x);
#else
    return exp2f(x);
#endif
}

// ---------------------------------------------------------------------------
// Kernel 1: one block per batch row b. y = in[b] @ w + bias; derive params
//   [mu0, mu1, a/s, s/L11 | s/L22, weight/(2*pi*L11*L22), 0, 0]
// ---------------------------------------------------------------------------
__global__ __launch_bounds__(128) void mdn_setup(
    const float* __restrict__ in,     // [B][D]
    const float* __restrict__ w,      // [D][UNITS]
    const float* __restrict__ bias,   // [UNITS]
    float* __restrict__ params)       // [B][K][8]
{
    const int b = blockIdx.x;
    const int u = threadIdx.x;        // 0..127

    __shared__ float insh[Dd];
    __shared__ float ysh[UNITS];

    insh[u] = in[b * Dd + u];
    __syncthreads();

    if (u < UNITS) {
        float a0 = 0.f, a1 = 0.f, a2 = 0.f, a3 = 0.f;
        #pragma unroll 8
        for (int d = 0; d < Dd; d += 4) {
            a0 = fmaf(insh[d + 0], w[(d + 0) * UNITS + u], a0);
            a1 = fmaf(insh[d + 1], w[(d + 1) * UNITS + u], a1);
            a2 = fmaf(insh[d + 2], w[(d + 2) * UNITS + u], a2);
            a3 = fmaf(insh[d + 3], w[(d + 3) * UNITS + u], a3);
        }
        ysh[u] = (a0 + a1) + (a2 + a3) + bias[u];
    }
    __syncthreads();

    if (u < Kk) {
        // each of the 16 lanes redundantly computes the softmax denominator
        float pmax = -3.4e38f;
        #pragma unroll
        for (int k = 0; k < Kk; ++k) pmax = fmaxf(pmax, ysh[5 * Kk + k]);
        float sum = 0.f;
        #pragma unroll
        for (int k = 0; k < Kk; ++k) sum += __expf(ysh[5 * Kk + k] - pmax);

        const int k = u;
        const float wgt = __expf(ysh[5 * Kk + k] - pmax) / sum;
        const float mu0 = ysh[2 * k];
        const float mu1 = ysh[2 * k + 1];
        const float a   = ysh[2 * Kk + 3 * k + 0];
        const float l22 = __expf(ysh[2 * Kk + 3 * k + 1]);
        const float l11 = __expf(ysh[2 * Kk + 3 * k + 2]);
        const float c   = wgt * INV_TWO_PI / (l11 * l22);

        float* o = params + (b * Kk + k) * 8;
        o[0] = mu0;
        o[1] = mu1;
        o[2] = a * INV_SCALE;       // a'
        o[3] = SCALE_S / l11;       // i11
        o[4] = SCALE_S / l22;       // i22
        o[5] = c;
        o[6] = 0.f;
        o[7] = 0.f;
    }
}

// ---------------------------------------------------------------------------
// Kernel 2: each thread owns 4 consecutive j in ONE row i, so per mixture k
// the x-dependent terms (z1, z1^2, u=(mu1+a'z1)*i22) are loop-invariant:
//   per point: z2 = fma(py, i22, -u); m = fma(z2,z2,z1sq); acc += c*exp2(-m)
// ---------------------------------------------------------------------------
__global__ __launch_bounds__(256) void mdn_eval(
    const float4* __restrict__ params,   // [B][K][2] float4
    float* __restrict__ out)             // [B][G]
{
    const int b = blockIdx.y;
    const unsigned gid = blockIdx.x * 256u + threadIdx.x;
    if (gid >= (unsigned)THREADS_PER_B) return;

    const unsigned i  = gid / (unsigned)JT;      // row (magic-mul)
    const unsigned jt = gid - i * (unsigned)JT;  // 4-point group in row
    const unsigned j0 = jt * 4u;

    const float px = (float)i * (1.0f / (float)(NXg - 1));
    float py[4];
    #pragma unroll
    for (int t = 0; t < 4; ++t)
        py[t] = (float)(j0 + (unsigned)t) * (1.0f / (float)(NYg - 1));

    float acc[4] = {0.f, 0.f, 0.f, 0.f};
    const float4* pb = params + b * Kk * 2;

    #pragma unroll
    for (int k = 0; k < Kk; ++k) {
        const float4 lo = pb[2 * k];       // uniform -> scalar loads
        const float4 hi = pb[2 * k + 1];
        const float z1   = (px - lo.x) * lo.w;           // (px-mu0)*i11
        const float z1sq = z1 * z1;
        const float uq   = fmaf(lo.z, z1, lo.y) * hi.x;  // (mu1+a'z1)*i22
        const float i22  = hi.x;
        const float c    = hi.y;
        #pragma unroll
        for (int t = 0; t < 4; ++t) {
            const float z2 = fmaf(py[t], i22, -uq);
            const float m  = fmaf(z2, z2, z1sq);
            acc[t] = fmaf(c, fast_exp2(-m), acc[t]);
        }
    }

    float* op = out + (size_t)b * Gg + (size_t)i * NYg + j0;
    float2 r0; r0.x = acc[0]; r0.y = acc[1];
    if (jt < (unsigned)(JT - 1)) {
        float2 r1; r1.x = acc[2]; r1.y = acc[3];
        reinterpret_cast<float2*>(op)[0] = r0;
        reinterpret_cast<float2*>(op + 2)[0] = r1;
    } else {
        reinterpret_cast<float2*>(op)[0] = r0;   // j = 392, 393 only
    }
}

// ---------------------------------------------------------------------------
extern "C" void kernel_launch(void* const* d_in, const int* in_sizes, int n_in,
                              void* d_out, int out_size, void* d_ws, size_t ws_size,
                              hipStream_t stream) {
    const float* in   = (const float*)d_in[0];   // [16][128]
    const float* w    = (const float*)d_in[1];   // [128][96]
    const float* bias = (const float*)d_in[2];   // [96]
    float* out        = (float*)d_out;           // [16][302][394]
    float* params     = (float*)d_ws;            // [16][16][8] = 8 KiB

    mdn_setup<<<dim3(Bb, 1, 1), dim3(128, 1, 1), 0, stream>>>(in, w, bias, params);

    dim3 grid((THREADS_PER_B + 255) / 256, Bb, 1);   // (117, 16)
    mdn_eval<<<grid, dim3(256, 1, 1), 0, stream>>>(
        reinterpret_cast<const float4*>(params), out);
}